// Round 1
// baseline (337.152 us; speedup 1.0000x reference)
//
#include <hip/hip_runtime.h>
#include <math.h>

#define PI_F 3.14159265358979323846f

// Shapes: B=4, X=Y=Z=64, CIN=COUT=32, modes MX=MY=MZ=16.
// Reference semantics (note the unusual axes!):
//   fftn over (Y, Z, CIN); crop x<16, ky<16, kz<16 (ki full 32)
//   out_ft[b,o,x,ky,kz] = sum_ki xhat[b,ki,x,ky,kz] * w[ki,o,x,ky,kz]
//   zero-pad back; ifftn over (ky->y, kz->z, o->co); take real.
// => output is zero for x>=16; only x[:, :16] is read.

// ---------------- K1: forward z-DFT (N=64), keep kz<16, x<16 only ----------
// in : x [b][x][y][z][i]  float
// out: T1 [b][x<16][y][kz<16][i] float2
__global__ __launch_bounds__(256) void k_dft_z(const float* __restrict__ x,
                                               float2* __restrict__ T1) {
    int bid = blockIdx.x;            // (b*16 + xx)*64 + y
    int y  = bid & 63;
    int xx = (bid >> 6) & 15;
    int b  = bid >> 10;
    __shared__ float  sx[2048];      // [z][i]  8KB
    __shared__ float2 tw[1024];      // [kz][z] 8KB
    const float* src = x + (size_t)((b * 64 + xx) * 64 + y) * 2048;
    for (int t = threadIdx.x; t < 2048; t += 256) sx[t] = src[t];
    const float c = -2.0f * PI_F / 64.0f;
    for (int t = threadIdx.x; t < 1024; t += 256) {
        int kz = t >> 6, z = t & 63;
        float s, cc; sincosf(c * (float)((kz * z) & 63), &s, &cc);
        tw[t] = make_float2(cc, s);
    }
    __syncthreads();
    float2* dst = T1 + (size_t)((b * 16 + xx) * 64 + y) * 512;
    for (int o = threadIdx.x; o < 512; o += 256) {
        int kz = o >> 5, i = o & 31;
        float ar = 0.f, ai = 0.f;
        for (int z = 0; z < 64; ++z) {
            float  v = sx[z * 32 + i];
            float2 t = tw[kz * 64 + z];
            ar = fmaf(v, t.x, ar);
            ai = fmaf(v, t.y, ai);
        }
        dst[o] = make_float2(ar, ai);
    }
}

// ---------------- K2: forward y-DFT (N=64), keep ky<16 ---------------------
// in : T1 [b][x][y][kz][i], out: XH [b][x][ky<16][kz][i]
__global__ __launch_bounds__(256) void k_dft_y(const float2* __restrict__ T1,
                                               float2* __restrict__ XH) {
    int bid = blockIdx.x;            // (b*16 + xx)*16 + kz
    int kz = bid & 15;
    int bx = bid >> 4;               // b*16+xx
    __shared__ float2 sT[2048];      // [y][i]  16KB
    __shared__ float2 tw[1024];      // [ky][y] 8KB
    const float2* src = T1 + (size_t)bx * 64 * 512 + kz * 32;
    for (int t = threadIdx.x; t < 2048; t += 256) {
        int y = t >> 5, i = t & 31;
        sT[t] = src[(size_t)y * 512 + i];
    }
    const float c = -2.0f * PI_F / 64.0f;
    for (int t = threadIdx.x; t < 1024; t += 256) {
        int ky = t >> 6, y = t & 63;
        float s, cc; sincosf(c * (float)((ky * y) & 63), &s, &cc);
        tw[t] = make_float2(cc, s);
    }
    __syncthreads();
    float2* dst = XH + (size_t)bx * 8192 + kz * 32;
    for (int o = threadIdx.x; o < 512; o += 256) {
        int ky = o >> 5, i = o & 31;
        float ar = 0.f, ai = 0.f;
        for (int y = 0; y < 64; ++y) {
            float2 a = sT[y * 32 + i];
            float2 t = tw[ky * 64 + y];
            ar = fmaf(a.x, t.x, fmaf(-a.y, t.y, ar));
            ai = fmaf(a.x, t.y, fmaf( a.y, t.x, ai));
        }
        dst[(size_t)ky * 512 + i] = make_float2(ar, ai);
    }
}

// ---------------- K3: forward channel-DFT (N=32) ---------------------------
// in : XH [b][x][ky][kz][i], out: X2 [b][ki][x][ky][kz]
__global__ __launch_bounds__(256) void k_dft_i(const float2* __restrict__ XH,
                                               float2* __restrict__ X2) {
    int bid = blockIdx.x;            // (b*16+xx)*16 + ky
    int ky = bid & 15;
    int xx = (bid >> 4) & 15;
    int b  = bid >> 8;
    __shared__ float2 sX[16 * 33];   // [kz][i] padded (stride 33 breaks 16-way conflict)
    __shared__ float2 tw[32 * 33];   // [ki][i] padded
    const float2* src = XH + (size_t)bid * 512;
    for (int t = threadIdx.x; t < 512; t += 256) {
        int kz = t >> 5, i = t & 31;
        sX[kz * 33 + i] = src[t];
    }
    const float c = -2.0f * PI_F / 32.0f;
    for (int t = threadIdx.x; t < 1024; t += 256) {
        int ki = t >> 5, i = t & 31;
        float s, cc; sincosf(c * (float)((ki * i) & 31), &s, &cc);
        tw[ki * 33 + i] = make_float2(cc, s);
    }
    __syncthreads();
    for (int o = threadIdx.x; o < 512; o += 256) {
        int ki = o >> 4, kz = o & 15;
        float ar = 0.f, ai = 0.f;
        for (int i = 0; i < 32; ++i) {
            float2 a = sX[kz * 33 + i];
            float2 t = tw[ki * 33 + i];
            ar = fmaf(a.x, t.x, fmaf(-a.y, t.y, ar));
            ai = fmaf(a.x, t.y, fmaf( a.y, t.x, ai));
        }
        X2[((size_t)(b * 32 + ki) * 16 + xx) * 256 + ky * 16 + kz] = make_float2(ar, ai);
    }
}

// ---------------- K4: per-mode complex contraction over ki -----------------
// in : X2 [b][ki][x][ky][kz]; wr/wi [ki][o][x][ky][kz]
// out: F  [b][x][ky][kz][o]
__global__ __launch_bounds__(256) void k_wmul(const float2* __restrict__ X2,
                                              const float* __restrict__ wr,
                                              const float* __restrict__ wi,
                                              float2* __restrict__ F) {
    int bid = blockIdx.x;            // x*16 + ky
    int ky = bid & 15, xx = bid >> 4;
    __shared__ float2 sX[4 * 32 * 16];   // [b][ki][kz] 16KB
    for (int t = threadIdx.x; t < 2048; t += 256) {
        int b = t >> 9, ki = (t >> 4) & 31, kz = t & 15;
        sX[t] = X2[((size_t)(b * 32 + ki) * 16 + xx) * 256 + ky * 16 + kz];
    }
    __syncthreads();
    int kz = threadIdx.x & 15;
    int o0 = threadIdx.x >> 4;       // [0,16)
    float2 acc[2][4];
    for (int h = 0; h < 2; ++h)
        for (int b = 0; b < 4; ++b) acc[h][b] = make_float2(0.f, 0.f);
    int wbase = xx * 256 + ky * 16 + kz;
    for (int ki = 0; ki < 32; ++ki) {
        for (int h = 0; h < 2; ++h) {
            int o = o0 + 16 * h;
            float wrv = wr[(size_t)(ki * 32 + o) * 4096 + wbase];
            float wiv = wi[(size_t)(ki * 32 + o) * 4096 + wbase];
            for (int b = 0; b < 4; ++b) {
                float2 a = sX[(b * 32 + ki) * 16 + kz];
                acc[h][b].x = fmaf(a.x, wrv, fmaf(-a.y, wiv, acc[h][b].x));
                acc[h][b].y = fmaf(a.x, wiv, fmaf( a.y, wrv, acc[h][b].y));
            }
        }
    }
    for (int h = 0; h < 2; ++h) {
        int o = o0 + 16 * h;
        for (int b = 0; b < 4; ++b)
            F[((size_t)((b * 16 + xx) * 16 + ky) * 16 + kz) * 32 + o] = acc[h][b];
    }
}

// ---------------- K5: inverse channel-DFT (o -> co, N=32) ------------------
// in : F [b][x][ky][kz][o], out: G [b][x][ky][kz][co]
__global__ __launch_bounds__(256) void k_idft_o(const float2* __restrict__ F,
                                                float2* __restrict__ G) {
    int bid = blockIdx.x;            // (b*16+xx)*16 + ky
    __shared__ float2 sF[16 * 33];   // [kz][o] padded
    __shared__ float2 tw[32 * 33];   // [co][o] padded
    const float2* src = F + (size_t)bid * 512;
    for (int t = threadIdx.x; t < 512; t += 256) {
        int kz = t >> 5, o = t & 31;
        sF[kz * 33 + o] = src[t];
    }
    const float c = 2.0f * PI_F / 32.0f;
    for (int t = threadIdx.x; t < 1024; t += 256) {
        int co = t >> 5, o = t & 31;
        float s, cc; sincosf(c * (float)((co * o) & 31), &s, &cc);
        tw[co * 33 + o] = make_float2(cc, s);
    }
    __syncthreads();
    float2* dst = G + (size_t)bid * 512;
    for (int t = threadIdx.x; t < 512; t += 256) {
        int kz = t >> 5, co = t & 31;
        float ar = 0.f, ai = 0.f;
        for (int o = 0; o < 32; ++o) {
            float2 a  = sF[kz * 33 + o];
            float2 tt = tw[co * 33 + o];
            ar = fmaf(a.x, tt.x, fmaf(-a.y, tt.y, ar));
            ai = fmaf(a.x, tt.y, fmaf( a.y, tt.x, ai));
        }
        dst[kz * 32 + co] = make_float2(ar, ai);
    }
}

// ---------------- K6: inverse z-DFT (kz<16 -> z=64) ------------------------
// in : G [b][x][ky][kz][co], out: H [b][x][ky][z][co]
__global__ __launch_bounds__(256) void k_idft_z(const float2* __restrict__ G,
                                                float2* __restrict__ H) {
    int bid = blockIdx.x;            // (b*16+xx)*16 + ky
    __shared__ float2 sG[512];       // [kz][co]
    __shared__ float2 tw[1024];      // [z][kz]
    const float2* src = G + (size_t)bid * 512;
    for (int t = threadIdx.x; t < 512; t += 256) sG[t] = src[t];
    const float c = 2.0f * PI_F / 64.0f;
    for (int t = threadIdx.x; t < 1024; t += 256) {
        int z = t >> 4, kz = t & 15;
        float s, cc; sincosf(c * (float)((kz * z) & 63), &s, &cc);
        tw[t] = make_float2(cc, s);
    }
    __syncthreads();
    float2* dst = H + (size_t)bid * 2048;
    int co = threadIdx.x & 31;
    int zg = threadIdx.x >> 5;       // [0,8)
    for (int j = 0; j < 8; ++j) {
        int z = zg * 8 + j;
        float ar = 0.f, ai = 0.f;
        for (int kz = 0; kz < 16; ++kz) {
            float2 a  = sG[kz * 32 + co];
            float2 tt = tw[z * 16 + kz];
            ar = fmaf(a.x, tt.x, fmaf(-a.y, tt.y, ar));
            ai = fmaf(a.x, tt.y, fmaf( a.y, tt.x, ai));
        }
        dst[z * 32 + co] = make_float2(ar, ai);
    }
}

// ---------------- K7: inverse y-DFT (ky<16 -> y=64), real, scale, zero-fill -
// in : H [b][x<16][ky][z][co], out: out [b][x][y][z][co] float
__global__ __launch_bounds__(256) void k_idft_y(const float2* __restrict__ H,
                                                float* __restrict__ out) {
    int bid = blockIdx.x;            // (b*64 + xx)*8 + zc
    int zc = bid & 7;
    int xx = (bid >> 3) & 63;
    int b  = bid >> 9;
    float* dst = out + (size_t)(b * 64 + xx) * 131072 + zc * 256;
    if (xx >= 16) {
        // zero region: 64 y x 8 z x 32 co = 16384 floats = 4096 float4
        for (int q = threadIdx.x; q < 4096; q += 256) {
            int y = q >> 6, r = q & 63;
            ((float4*)(dst + (size_t)y * 2048))[r] = make_float4(0.f, 0.f, 0.f, 0.f);
        }
        return;
    }
    __shared__ float2 sH[4096];      // [ky][dz][co] 32KB
    __shared__ float2 twy[1024];     // [y][ky]
    const float2* src = H + (size_t)(b * 16 + xx) * 32768 + zc * 256;
    for (int t = threadIdx.x; t < 4096; t += 256) {
        int ky = t >> 8, r = t & 255;
        sH[t] = src[(size_t)ky * 2048 + r];
    }
    const float c = 2.0f * PI_F / 64.0f;
    for (int t = threadIdx.x; t < 1024; t += 256) {
        int y = t >> 4, ky = t & 15;
        float s, cc; sincosf(c * (float)((ky * y) & 63), &s, &cc);
        twy[t] = make_float2(cc, s);
    }
    __syncthreads();
    const float scale = 1.0f / 131072.0f;
    int r = threadIdx.x;             // dz*32+co
    for (int y = 0; y < 64; ++y) {
        float ar = 0.f;
        for (int ky = 0; ky < 16; ++ky) {
            float2 a  = sH[ky * 256 + r];
            float2 tt = twy[y * 16 + ky];
            ar = fmaf(a.x, tt.x, fmaf(-a.y, tt.y, ar));
        }
        dst[(size_t)y * 2048 + r] = ar * scale;
    }
}

extern "C" void kernel_launch(void* const* d_in, const int* in_sizes, int n_in,
                              void* d_out, int out_size, void* d_ws, size_t ws_size,
                              hipStream_t stream) {
    const float* x  = (const float*)d_in[0];
    const float* wr = (const float*)d_in[1];
    const float* wi = (const float*)d_in[2];
    float* out = (float*)d_out;
    char*  ws  = (char*)d_ws;
    // Buffer A: 2,097,152 float2 (16.78 MB)  -- T1, later H
    // Buffer B:   524,288 float2 ( 4.19 MB)  -- XH, later F
    // Buffer C:   524,288 float2 ( 4.19 MB)  -- X2, later G
    float2* A = (float2*)ws;
    float2* Bv = (float2*)(ws + (size_t)2097152 * 8);
    float2* Cv = (float2*)(ws + (size_t)2097152 * 8 + (size_t)524288 * 8);

    k_dft_z <<<4096, 256, 0, stream>>>(x, A);        // x -> T1(A)
    k_dft_y <<<1024, 256, 0, stream>>>(A, Bv);       // T1 -> XH(B)
    k_dft_i <<<1024, 256, 0, stream>>>(Bv, Cv);      // XH -> X2(C)
    k_wmul  <<< 256, 256, 0, stream>>>(Cv, wr, wi, Bv); // X2,w -> F(B)
    k_idft_o<<<1024, 256, 0, stream>>>(Bv, Cv);      // F -> G(C)
    k_idft_z<<<1024, 256, 0, stream>>>(Cv, A);       // G -> H(A)
    k_idft_y<<<2048, 256, 0, stream>>>(A, out);      // H -> out (+zero fill)
}

// Round 2
// 292.962 us; speedup vs baseline: 1.1508x; 1.1508x over previous
//
#include <hip/hip_runtime.h>
#include <math.h>

#define PI_F 3.14159265358979323846f

// Shapes: B=4, X=Y=Z=64, CIN=COUT=32, modes 16.
// Reference transforms (Y, Z, CIN); crop x<16, ky<16, kz<16; einsum over ki;
// inverse over (ky->y, kz->z, o->co); real part; output zero for x>=16.
//
// 4 kernels, all register-tiled so ds:fma ratio is ~1:10+:
//  KA z-DFT   : x[b,x<16,y,z,i] -> T1[b,x,y,kz<16,i]      (complex)
//  KB y-DFT   : T1 -> XH[b,x,ky<16,kz,i]
//  KC fused   : i-DFT(32) + w-mul + o-IDFT(32): XH -> G[b,x,ky,kz,co]
//  KD fused   : z-IDFT + y-IDFT + Re + 1/131072 + zero-fill -> out[b,x,y,z,co]

// ---------------- KA: forward z-DFT ----------------------------------------
// grid 512 = (b4, x16, yg8); block 256; tile/thread = 2kz x 8i, y per thread.
__global__ __launch_bounds__(256) void k_dft_z(const float* __restrict__ x,
                                               float2* __restrict__ T1) {
    int bid = blockIdx.x;
    int yg = bid & 7, xx = (bid >> 3) & 15, b = bid >> 7;
    __shared__ float  sx[16384];     // [y8][z][i] 64KB
    __shared__ float2 twt[1024];     // [z][kz]    8KB
    float4* sx4 = (float4*)sx;
    const float4* src4 = (const float4*)(x + (size_t)((b * 64 + xx) * 64 + yg * 8) * 2048);
    #pragma unroll
    for (int t = threadIdx.x; t < 4096; t += 256) sx4[t] = src4[t];
    const float cn = -2.0f * PI_F / 64.0f;
    for (int t = threadIdx.x; t < 1024; t += 256) {
        int z = t >> 4, kz = t & 15;
        float s, c; sincosf(cn * (float)((z * kz) & 63), &s, &c);
        twt[t] = make_float2(c, s);
    }
    __syncthreads();
    int ig = threadIdx.x & 3, kz2 = (threadIdx.x >> 2) & 7, y8 = threadIdx.x >> 5;
    float ar0[8], ai0[8], ar1[8], ai1[8];
    #pragma unroll
    for (int j = 0; j < 8; j++) { ar0[j] = ai0[j] = ar1[j] = ai1[j] = 0.f; }
    const float4* twv = (const float4*)twt;   // [z][8]: (c0,s0,c1,s1) per kz-pair
    #pragma unroll 4
    for (int z = 0; z < 64; z++) {
        float4 va = sx4[(y8 * 64 + z) * 8 + ig * 2];
        float4 vb = sx4[(y8 * 64 + z) * 8 + ig * 2 + 1];
        float4 tp = twv[z * 8 + kz2];
        float v[8] = {va.x, va.y, va.z, va.w, vb.x, vb.y, vb.z, vb.w};
        #pragma unroll
        for (int j = 0; j < 8; j++) {
            ar0[j] = fmaf(v[j], tp.x, ar0[j]);
            ai0[j] = fmaf(v[j], tp.y, ai0[j]);
            ar1[j] = fmaf(v[j], tp.z, ar1[j]);
            ai1[j] = fmaf(v[j], tp.w, ai1[j]);
        }
    }
    int y = yg * 8 + y8, kz0 = kz2 * 2, i0 = ig * 8;
    float2* dst = T1 + (size_t)((b * 16 + xx) * 64 + y) * 512;
    float4* d0 = (float4*)(dst + kz0 * 32 + i0);
    d0[0] = make_float4(ar0[0], ai0[0], ar0[1], ai0[1]);
    d0[1] = make_float4(ar0[2], ai0[2], ar0[3], ai0[3]);
    d0[2] = make_float4(ar0[4], ai0[4], ar0[5], ai0[5]);
    d0[3] = make_float4(ar0[6], ai0[6], ar0[7], ai0[7]);
    float4* d1 = (float4*)(dst + (kz0 + 1) * 32 + i0);
    d1[0] = make_float4(ar1[0], ai1[0], ar1[1], ai1[1]);
    d1[1] = make_float4(ar1[2], ai1[2], ar1[3], ai1[3]);
    d1[2] = make_float4(ar1[4], ai1[4], ar1[5], ai1[5]);
    d1[3] = make_float4(ar1[6], ai1[6], ar1[7], ai1[7]);
}

// ---------------- KB: forward y-DFT ----------------------------------------
// grid 256 = (b4, x16, kzg4); block 256; tile/thread = 2ky x 4i at one kz.
__global__ __launch_bounds__(256) void k_dft_y(const float2* __restrict__ T1,
                                               float2* __restrict__ XH) {
    int bid = blockIdx.x;
    int kzg = bid & 3, xx = (bid >> 2) & 15, b = bid >> 6;
    __shared__ float2 sT[4 * 2178];  // [kz4][y(stride 34)][i]  ~70KB
    __shared__ float2 twt[1024];     // [y][ky] 8KB
    float4* sT4 = (float4*)sT;
    const float4* Tg4 = (const float4*)T1;
    size_t gbase = (size_t)(b * 16 + xx) * 64 * 256 + (size_t)kzg * 64;  // f4 units
    for (int t = threadIdx.x; t < 4096; t += 256) {
        int y = t >> 6, kz4 = (t >> 4) & 3, i4 = t & 15;
        sT4[kz4 * 1089 + y * 17 + i4] = Tg4[gbase + (size_t)y * 256 + kz4 * 16 + i4];
    }
    const float cn = -2.0f * PI_F / 64.0f;
    for (int t = threadIdx.x; t < 1024; t += 256) {
        int y = t >> 4, ky = t & 15;
        float s, c; sincosf(cn * (float)((y * ky) & 63), &s, &c);
        twt[t] = make_float2(c, s);
    }
    __syncthreads();
    int ig = threadIdx.x & 7, ky2 = (threadIdx.x >> 3) & 7, kz4 = threadIdx.x >> 6;
    float ar[2][4], ai[2][4];
    #pragma unroll
    for (int h = 0; h < 2; h++)
        #pragma unroll
        for (int j = 0; j < 4; j++) { ar[h][j] = ai[h][j] = 0.f; }
    const float4* twv = (const float4*)twt;
    #pragma unroll 4
    for (int y = 0; y < 64; y++) {
        float4 a01 = sT4[kz4 * 1089 + y * 17 + ig * 2];
        float4 a23 = sT4[kz4 * 1089 + y * 17 + ig * 2 + 1];
        float4 tp = twv[y * 8 + ky2];   // c0,s0,c1,s1
        float xr[4] = {a01.x, a01.z, a23.x, a23.z};
        float xi[4] = {a01.y, a01.w, a23.y, a23.w};
        #pragma unroll
        for (int j = 0; j < 4; j++) {
            ar[0][j] += xr[j] * tp.x - xi[j] * tp.y;
            ai[0][j] += xr[j] * tp.y + xi[j] * tp.x;
            ar[1][j] += xr[j] * tp.z - xi[j] * tp.w;
            ai[1][j] += xr[j] * tp.w + xi[j] * tp.z;
        }
    }
    int kz = kzg * 4 + kz4, i0 = ig * 4;
    #pragma unroll
    for (int h = 0; h < 2; h++) {
        int ky = ky2 * 2 + h;
        float2* dp = XH + (((size_t)(b * 16 + xx) * 16 + ky) * 16 + kz) * 32 + i0;
        ((float4*)dp)[0] = make_float4(ar[h][0], ai[h][0], ar[h][1], ai[h][1]);
        ((float4*)dp)[1] = make_float4(ar[h][2], ai[h][2], ar[h][3], ai[h][3]);
    }
}

// ---------------- KC: fused i-DFT + w-mul + o-IDFT -------------------------
// grid 256 = (x16, ky16); block 256; all 4 b handled via wave split.
__global__ __launch_bounds__(256) void k_mid(const float2* __restrict__ XH,
                                             const float* __restrict__ wr,
                                             const float* __restrict__ wi,
                                             float2* __restrict__ G) {
    int bid = blockIdx.x;
    int ky = bid & 15, xx = bid >> 4;
    __shared__ float2 sA[4 * 528];   // [b][kz(stride33)][i] ; reused as F[b][kz][o]
    __shared__ float2 sB[4 * 576];   // [b][ki(stride18)][kz]
    __shared__ float2 twt[1024];     // [m][k] = exp(-2pi i mk/32)
    for (int t = threadIdx.x; t < 2048; t += 256) {
        int b = t >> 9, kz = (t >> 5) & 15, i = t & 31;
        sA[b * 528 + kz * 33 + i] =
            XH[(((size_t)(b * 16 + xx) * 16 + ky) * 16 + kz) * 32 + i];
    }
    const float cn32 = -2.0f * PI_F / 32.0f;
    for (int t = threadIdx.x; t < 1024; t += 256) {
        int m = t >> 5, k = t & 31;
        float s, c; sincosf(cn32 * (float)((m * k) & 31), &s, &c);
        twt[t] = make_float2(c, s);
    }
    __syncthreads();
    const float4* twv = (const float4*)twt;
    // phase 1: X2[b][ki][kz] = sum_i tw[ki,i] * XH[b][kz][i]   (tile 8ki x 1kz)
    {
        int kz = threadIdx.x & 15, ki8 = (threadIdx.x >> 4) & 3, b = threadIdx.x >> 6;
        float xr[8], xi[8];
        #pragma unroll
        for (int j = 0; j < 8; j++) { xr[j] = xi[j] = 0.f; }
        #pragma unroll 4
        for (int i = 0; i < 32; i++) {
            float2 a = sA[b * 528 + kz * 33 + i];
            #pragma unroll
            for (int k = 0; k < 4; k++) {
                float4 tp = twv[i * 16 + ki8 * 4 + k];
                xr[2 * k]     += a.x * tp.x - a.y * tp.y;
                xi[2 * k]     += a.x * tp.y + a.y * tp.x;
                xr[2 * k + 1] += a.x * tp.z - a.y * tp.w;
                xi[2 * k + 1] += a.x * tp.w + a.y * tp.z;
            }
        }
        #pragma unroll
        for (int j = 0; j < 8; j++)
            sB[b * 576 + (ki8 * 8 + j) * 18 + kz] = make_float2(xr[j], xi[j]);
    }
    __syncthreads();
    // phase 2: F[b][kz][o] = sum_ki X2[b][ki][kz] * w[ki,o]   (tile 2o x 4kz)
    {
        int kzg = threadIdx.x & 3, o2 = (threadIdx.x >> 2) & 15, b = threadIdx.x >> 6;
        int wbase = xx * 256 + ky * 16 + kzg * 4;
        float Fr[2][4], Fi[2][4];
        #pragma unroll
        for (int h = 0; h < 2; h++)
            #pragma unroll
            for (int q = 0; q < 4; q++) { Fr[h][q] = Fi[h][q] = 0.f; }
        const float4* sB4 = (const float4*)sB;
        #pragma unroll 4
        for (int ki = 0; ki < 32; ki++) {
            float4 a01 = sB4[b * 288 + ki * 9 + kzg * 2];
            float4 a23 = sB4[b * 288 + ki * 9 + kzg * 2 + 1];
            float xr[4] = {a01.x, a01.z, a23.x, a23.z};
            float xi[4] = {a01.y, a01.w, a23.y, a23.w};
            #pragma unroll
            for (int ol = 0; ol < 2; ol++) {
                int o = o2 * 2 + ol;
                float4 w4r = *(const float4*)(wr + (size_t)(ki * 32 + o) * 4096 + wbase);
                float4 w4i = *(const float4*)(wi + (size_t)(ki * 32 + o) * 4096 + wbase);
                float wrv[4] = {w4r.x, w4r.y, w4r.z, w4r.w};
                float wiv[4] = {w4i.x, w4i.y, w4i.z, w4i.w};
                #pragma unroll
                for (int q = 0; q < 4; q++) {
                    Fr[ol][q] += xr[q] * wrv[q] - xi[q] * wiv[q];
                    Fi[ol][q] += xr[q] * wiv[q] + xi[q] * wrv[q];
                }
            }
        }
        // write F into sA (XH no longer needed; nobody reads sA in phase 2)
        #pragma unroll
        for (int ol = 0; ol < 2; ol++) {
            int o = o2 * 2 + ol;
            #pragma unroll
            for (int q = 0; q < 4; q++) {
                int kz = kzg * 4 + q;
                sA[b * 528 + kz * 33 + o] = make_float2(Fr[ol][q], Fi[ol][q]);
            }
        }
    }
    __syncthreads();
    // phase 3: G[b][kz][co] = sum_o conj(tw[co,o]) * F[b][kz][o]  (tile 8co x 1kz)
    {
        int kz = threadIdx.x & 15, co8 = (threadIdx.x >> 4) & 3, b = threadIdx.x >> 6;
        float gr[8], gi[8];
        #pragma unroll
        for (int j = 0; j < 8; j++) { gr[j] = gi[j] = 0.f; }
        #pragma unroll 4
        for (int o = 0; o < 32; o++) {
            float2 f = sA[b * 528 + kz * 33 + o];
            #pragma unroll
            for (int k = 0; k < 4; k++) {
                float4 tp = twv[o * 16 + co8 * 4 + k];
                gr[2 * k]     += f.x * tp.x + f.y * tp.y;
                gi[2 * k]     += f.y * tp.x - f.x * tp.y;
                gr[2 * k + 1] += f.x * tp.z + f.y * tp.w;
                gi[2 * k + 1] += f.y * tp.z - f.x * tp.w;
            }
        }
        float2* dp = G + (((size_t)(b * 16 + xx) * 16 + ky) * 16 + kz) * 32 + co8 * 8;
        ((float4*)dp)[0] = make_float4(gr[0], gi[0], gr[1], gi[1]);
        ((float4*)dp)[1] = make_float4(gr[2], gi[2], gr[3], gi[3]);
        ((float4*)dp)[2] = make_float4(gr[4], gi[4], gr[5], gi[5]);
        ((float4*)dp)[3] = make_float4(gr[6], gi[6], gr[7], gi[7]);
    }
}

// ---------------- KD: fused z-IDFT + y-IDFT + Re + scale + zero-fill -------
// grid 2048 = (b4, x64, zc8); block 256. x>=16 -> pure zero-fill.
__global__ __launch_bounds__(256) void k_idft_zy(const float2* __restrict__ G,
                                                 float* __restrict__ out) {
    int bid = blockIdx.x;
    int zc = bid & 7, xx = (bid >> 3) & 63, b = bid >> 9;
    float* dstb = out + (size_t)(b * 64 + xx) * 131072;   // [y][z][co]
    if (xx >= 16) {
        float4* d4 = (float4*)dstb;
        for (int t = threadIdx.x; t < 4096; t += 256) {
            int y = t >> 6, r = t & 63;
            d4[(size_t)y * 512 + zc * 64 + r] = make_float4(0.f, 0.f, 0.f, 0.f);
        }
        return;
    }
    __shared__ float2 sH[128 * 34];  // row R=ky*8+dz, stride 34, [co]  ~34KB
    __shared__ float2 twy[1024];     // [ky][y] 8KB
    __shared__ float2 twz[8 * 17];   // [dz][kz] padded
    const float cp = 2.0f * PI_F / 64.0f;
    for (int t = threadIdx.x; t < 1024; t += 256) {
        int ky = t >> 6, y = t & 63;
        float s, c; sincosf(cp * (float)((ky * y) & 63), &s, &c);
        twy[t] = make_float2(c, s);
    }
    if (threadIdx.x < 128) {
        int dz = threadIdx.x >> 4, kz = threadIdx.x & 15;
        int z = zc * 8 + dz;
        float s, c; sincosf(cp * (float)((kz * z) & 63), &s, &c);
        twz[dz * 17 + kz] = make_float2(c, s);
    }
    __syncthreads();
    // phase Z: H[ky][dz][co] = sum_kz twz[dz,kz] * G[ky][kz][co]
    // lanes (ky16, dz8, coh2); G read from global (dz-lanes share addresses ->
    // coalescer merges; slice is L2-resident, re-read 8x across zc-blocks).
    {
        int coh = threadIdx.x & 1, dz = (threadIdx.x >> 1) & 7, ky = threadIdx.x >> 4;
        const float2* Gb = G + ((size_t)(b * 16 + xx) * 16 + ky) * 512 + coh * 16;
        float Hr[16], Hi[16];
        #pragma unroll
        for (int j = 0; j < 16; j++) { Hr[j] = Hi[j] = 0.f; }
        #pragma unroll 2
        for (int kz = 0; kz < 16; kz++) {
            float2 tz = twz[dz * 17 + kz];
            #pragma unroll
            for (int k = 0; k < 8; k++) {
                float4 g = *(const float4*)(Gb + kz * 32 + k * 2);
                Hr[2 * k]     += g.x * tz.x - g.y * tz.y;
                Hi[2 * k]     += g.x * tz.y + g.y * tz.x;
                Hr[2 * k + 1] += g.z * tz.x - g.w * tz.y;
                Hi[2 * k + 1] += g.z * tz.y + g.w * tz.x;
            }
        }
        float2* hp = sH + (ky * 8 + dz) * 34 + coh * 16;
        #pragma unroll
        for (int k = 0; k < 8; k++)
            *(float4*)(hp + k * 2) = make_float4(Hr[2 * k], Hi[2 * k], Hr[2 * k + 1], Hi[2 * k + 1]);
    }
    __syncthreads();
    // phase Y: out[y][dz][co] = Re sum_ky twy[y,ky] * H[ky][dz][co]
    // lanes (yg8, dz8, cog4); tile 8y x 8co per thread.
    {
        int cog = threadIdx.x & 3, dz = (threadIdx.x >> 2) & 7, yg = threadIdx.x >> 5;
        float acc[8][8];
        #pragma unroll
        for (int yl = 0; yl < 8; yl++)
            #pragma unroll
            for (int cl = 0; cl < 8; cl++) acc[yl][cl] = 0.f;
        const float4* twy4 = (const float4*)twy;
        const float4* sH4 = (const float4*)sH;
        for (int ky = 0; ky < 16; ky++) {
            float4 t0 = twy4[ky * 32 + yg * 4 + 0];
            float4 t1 = twy4[ky * 32 + yg * 4 + 1];
            float4 t2 = twy4[ky * 32 + yg * 4 + 2];
            float4 t3 = twy4[ky * 32 + yg * 4 + 3];
            float4 h0 = sH4[(ky * 8 + dz) * 17 + cog * 4 + 0];
            float4 h1 = sH4[(ky * 8 + dz) * 17 + cog * 4 + 1];
            float4 h2 = sH4[(ky * 8 + dz) * 17 + cog * 4 + 2];
            float4 h3 = sH4[(ky * 8 + dz) * 17 + cog * 4 + 3];
            float tc[8] = {t0.x, t0.z, t1.x, t1.z, t2.x, t2.z, t3.x, t3.z};
            float ts[8] = {t0.y, t0.w, t1.y, t1.w, t2.y, t2.w, t3.y, t3.w};
            float hr[8] = {h0.x, h0.z, h1.x, h1.z, h2.x, h2.z, h3.x, h3.z};
            float hi[8] = {h0.y, h0.w, h1.y, h1.w, h2.y, h2.w, h3.y, h3.w};
            #pragma unroll
            for (int yl = 0; yl < 8; yl++)
                #pragma unroll
                for (int cl = 0; cl < 8; cl++)
                    acc[yl][cl] += tc[yl] * hr[cl] - ts[yl] * hi[cl];
        }
        const float sc = 1.0f / 131072.0f;
        #pragma unroll
        for (int yl = 0; yl < 8; yl++) {
            int y = yg * 8 + yl;
            float4* d4 = (float4*)(dstb + ((size_t)y * 64 + zc * 8 + dz) * 32 + cog * 8);
            d4[0] = make_float4(acc[yl][0] * sc, acc[yl][1] * sc, acc[yl][2] * sc, acc[yl][3] * sc);
            d4[1] = make_float4(acc[yl][4] * sc, acc[yl][5] * sc, acc[yl][6] * sc, acc[yl][7] * sc);
        }
    }
}

extern "C" void kernel_launch(void* const* d_in, const int* in_sizes, int n_in,
                              void* d_out, int out_size, void* d_ws, size_t ws_size,
                              hipStream_t stream) {
    const float* x  = (const float*)d_in[0];
    const float* wr = (const float*)d_in[1];
    const float* wi = (const float*)d_in[2];
    float* out = (float*)d_out;
    char*  ws  = (char*)d_ws;
    // T1: 2,097,152 f2 (16.8 MB); XH: 524,288 f2 (4.2 MB); G: 524,288 f2 (4.2 MB)
    float2* T1 = (float2*)ws;
    float2* XH = (float2*)(ws + (size_t)16777216);
    float2* Gb = (float2*)(ws + (size_t)16777216 + 4194304);

    k_dft_z  <<< 512, 256, 0, stream>>>(x, T1);
    k_dft_y  <<< 256, 256, 0, stream>>>(T1, XH);
    k_mid    <<< 256, 256, 0, stream>>>(XH, wr, wi, Gb);
    k_idft_zy<<<2048, 256, 0, stream>>>(Gb, out);
}

// Round 3
// 288.100 us; speedup vs baseline: 1.1703x; 1.0169x over previous
//
#include <hip/hip_runtime.h>
#include <math.h>

#define PI_F 3.14159265358979323846f

// Shapes: B=4, X=Y=Z=64, CIN=COUT=32, modes 16.
// Reference transforms (Y, Z, CIN); crop x<16, ky<16, kz<16; einsum over ki;
// inverse over (ky->y, kz->z, o->co); real part; output zero for x>=16.
//
//  K1 z-DFT   : x[b,x<16,y,z,i] -> T1[b,x,y,kz<16,i]   (i-half split, 4 blk/CU)
//  K2 y-DFT   : T1 -> XH[b,x,ky<16,kz,i]               (i-half split, 3 blk/CU)
//  K3 fused   : i-DFT(32) + w-mul + o-IDFT(32): XH -> G[b,x,ky,kz,co]
//  K4 fused   : z-IDFT + y-IDFT + Re + 1/131072 + zero-fill -> out[b,x,y,z,co]

// ---------------- K1: forward z-DFT ----------------------------------------
// grid 1024 = (b4, x16, yg8, ih2); block 256; tile 2kz x 4i per thread.
__global__ __launch_bounds__(256) void k_dft_z(const float* __restrict__ x,
                                               float2* __restrict__ T1) {
    int bid = blockIdx.x;
    int ih = bid & 1, yg = (bid >> 1) & 7, xx = (bid >> 4) & 15, b = bid >> 8;
    __shared__ float  sx[8192];      // [y8][z64][i16] 32KB
    __shared__ float2 twt[1024];     // [z][kz16] 8KB
    float4* sx4 = (float4*)sx;
    const float4* src4 = (const float4*)(x + (size_t)((b * 64 + xx) * 64 + yg * 8) * 2048) + ih * 4;
    #pragma unroll
    for (int t = threadIdx.x; t < 2048; t += 256) {
        int i4 = t & 3, z = (t >> 2) & 63, y = t >> 8;
        sx4[(y * 64 + z) * 4 + i4] = src4[(size_t)y * 512 + z * 8 + i4];
    }
    const float cn = -2.0f * PI_F / 64.0f;
    for (int t = threadIdx.x; t < 1024; t += 256) {
        int z = t >> 4, kz = t & 15;
        float s, c; sincosf(cn * (float)((z * kz) & 63), &s, &c);
        twt[t] = make_float2(c, s);
    }
    __syncthreads();
    int ig = threadIdx.x & 3, kz2 = (threadIdx.x >> 2) & 7, y8 = threadIdx.x >> 5;
    float ar0[4], ai0[4], ar1[4], ai1[4];
    #pragma unroll
    for (int j = 0; j < 4; j++) { ar0[j] = ai0[j] = ar1[j] = ai1[j] = 0.f; }
    const float4* twv = (const float4*)twt;   // [z][8]: (c0,s0,c1,s1) per kz-pair
    #pragma unroll 8
    for (int z = 0; z < 64; z++) {
        float4 va = sx4[(y8 * 64 + z) * 4 + ig];
        float4 tp = twv[z * 8 + kz2];
        float v[4] = {va.x, va.y, va.z, va.w};
        #pragma unroll
        for (int j = 0; j < 4; j++) {
            ar0[j] = fmaf(v[j], tp.x, ar0[j]);
            ai0[j] = fmaf(v[j], tp.y, ai0[j]);
            ar1[j] = fmaf(v[j], tp.z, ar1[j]);
            ai1[j] = fmaf(v[j], tp.w, ai1[j]);
        }
    }
    int y = yg * 8 + y8, kz0 = kz2 * 2, i0 = ih * 16 + ig * 4;
    float2* dst = T1 + (size_t)((b * 16 + xx) * 64 + y) * 512;
    float4* d0 = (float4*)(dst + kz0 * 32 + i0);
    d0[0] = make_float4(ar0[0], ai0[0], ar0[1], ai0[1]);
    d0[1] = make_float4(ar0[2], ai0[2], ar0[3], ai0[3]);
    float4* d1 = (float4*)(dst + (kz0 + 1) * 32 + i0);
    d1[0] = make_float4(ar1[0], ai1[0], ar1[1], ai1[1]);
    d1[1] = make_float4(ar1[2], ai1[2], ar1[3], ai1[3]);
}

// ---------------- K2: forward y-DFT ----------------------------------------
// grid 512 = (b4, x16, kzg4, ih2); block 256; tile 2ky x 2i per thread.
__global__ __launch_bounds__(256) void k_dft_y(const float2* __restrict__ T1,
                                               float2* __restrict__ XH) {
    int bid = blockIdx.x;
    int ih = bid & 1, kzg = (bid >> 1) & 3, xx = (bid >> 3) & 15, b = bid >> 7;
    __shared__ float4 sT4[2304];     // [kz4][y(stride 9)][i4 8] ~37KB
    __shared__ float2 twt[1024];     // [y][ky16] 8KB
    const float4* Tg4 = (const float4*)T1;
    size_t gbase = (size_t)(b * 16 + xx) * 64 * 256;
    #pragma unroll
    for (int t = threadIdx.x; t < 2048; t += 256) {
        int i4 = t & 7, kz4 = (t >> 3) & 3, y = t >> 5;
        sT4[kz4 * 576 + y * 9 + i4] =
            Tg4[gbase + (size_t)y * 256 + (kzg * 4 + kz4) * 16 + ih * 8 + i4];
    }
    const float cn = -2.0f * PI_F / 64.0f;
    for (int t = threadIdx.x; t < 1024; t += 256) {
        int y = t >> 4, ky = t & 15;
        float s, c; sincosf(cn * (float)((y * ky) & 63), &s, &c);
        twt[t] = make_float2(c, s);
    }
    __syncthreads();
    int ig = threadIdx.x & 7, ky2 = (threadIdx.x >> 3) & 7, kz4 = threadIdx.x >> 6;
    float ar[2][2], ai[2][2];
    #pragma unroll
    for (int h = 0; h < 2; h++) { ar[h][0] = ar[h][1] = ai[h][0] = ai[h][1] = 0.f; }
    const float4* twv = (const float4*)twt;
    #pragma unroll 8
    for (int y = 0; y < 64; y++) {
        float4 a  = sT4[kz4 * 576 + y * 9 + ig];   // (xr0,xi0,xr1,xi1)
        float4 tp = twv[y * 8 + ky2];              // (c0,s0,c1,s1)
        float xr[2] = {a.x, a.z}, xi[2] = {a.y, a.w};
        #pragma unroll
        for (int j = 0; j < 2; j++) {
            ar[0][j] += xr[j] * tp.x - xi[j] * tp.y;
            ai[0][j] += xr[j] * tp.y + xi[j] * tp.x;
            ar[1][j] += xr[j] * tp.z - xi[j] * tp.w;
            ai[1][j] += xr[j] * tp.w + xi[j] * tp.z;
        }
    }
    int kz = kzg * 4 + kz4;
    #pragma unroll
    for (int h = 0; h < 2; h++) {
        int ky = ky2 * 2 + h;
        float2* dp = XH + (((size_t)(b * 16 + xx) * 16 + ky) * 16 + kz) * 32 + ih * 16 + ig * 2;
        *(float4*)dp = make_float4(ar[h][0], ai[h][0], ar[h][1], ai[h][1]);
    }
}

// ---------------- K3: fused i-DFT + w-mul + o-IDFT -------------------------
// grid 256 = (x16, ky16); block 256; all 4 b handled via wave split.
__global__ __launch_bounds__(256) void k_mid(const float2* __restrict__ XH,
                                             const float* __restrict__ wr,
                                             const float* __restrict__ wi,
                                             float2* __restrict__ G) {
    int bid = blockIdx.x;
    int ky = bid & 15, xx = bid >> 4;
    __shared__ float2 sA[4 * 528];   // [b][kz(stride33)][i] ; reused as F[b][kz][o]
    __shared__ float2 sB[4 * 576];   // [b][ki(stride18)][kz]
    __shared__ float2 twt[1024];     // [m][k] = exp(-2pi i mk/32)
    for (int t = threadIdx.x; t < 2048; t += 256) {
        int b = t >> 9, kz = (t >> 5) & 15, i = t & 31;
        sA[b * 528 + kz * 33 + i] =
            XH[(((size_t)(b * 16 + xx) * 16 + ky) * 16 + kz) * 32 + i];
    }
    const float cn32 = -2.0f * PI_F / 32.0f;
    for (int t = threadIdx.x; t < 1024; t += 256) {
        int m = t >> 5, k = t & 31;
        float s, c; sincosf(cn32 * (float)((m * k) & 31), &s, &c);
        twt[t] = make_float2(c, s);
    }
    __syncthreads();
    const float4* twv = (const float4*)twt;
    // phase 1: X2[b][ki][kz] = sum_i tw[ki,i] * XH[b][kz][i]   (tile 8ki x 1kz)
    {
        int kz = threadIdx.x & 15, ki8 = (threadIdx.x >> 4) & 3, b = threadIdx.x >> 6;
        float xr[8], xi[8];
        #pragma unroll
        for (int j = 0; j < 8; j++) { xr[j] = xi[j] = 0.f; }
        #pragma unroll 4
        for (int i = 0; i < 32; i++) {
            float2 a = sA[b * 528 + kz * 33 + i];
            #pragma unroll
            for (int k = 0; k < 4; k++) {
                float4 tp = twv[i * 16 + ki8 * 4 + k];
                xr[2 * k]     += a.x * tp.x - a.y * tp.y;
                xi[2 * k]     += a.x * tp.y + a.y * tp.x;
                xr[2 * k + 1] += a.x * tp.z - a.y * tp.w;
                xi[2 * k + 1] += a.x * tp.w + a.y * tp.z;
            }
        }
        #pragma unroll
        for (int j = 0; j < 8; j++)
            sB[b * 576 + (ki8 * 8 + j) * 18 + kz] = make_float2(xr[j], xi[j]);
    }
    __syncthreads();
    // phase 2: F[b][kz][o] = sum_ki X2[b][ki][kz] * w[ki,o]   (tile 2o x 4kz)
    {
        int kzg = threadIdx.x & 3, o2 = (threadIdx.x >> 2) & 15, b = threadIdx.x >> 6;
        int wbase = xx * 256 + ky * 16 + kzg * 4;
        float Fr[2][4], Fi[2][4];
        #pragma unroll
        for (int h = 0; h < 2; h++)
            #pragma unroll
            for (int q = 0; q < 4; q++) { Fr[h][q] = Fi[h][q] = 0.f; }
        const float4* sB4 = (const float4*)sB;
        #pragma unroll 4
        for (int ki = 0; ki < 32; ki++) {
            float4 a01 = sB4[b * 288 + ki * 9 + kzg * 2];
            float4 a23 = sB4[b * 288 + ki * 9 + kzg * 2 + 1];
            float xr[4] = {a01.x, a01.z, a23.x, a23.z};
            float xi[4] = {a01.y, a01.w, a23.y, a23.w};
            #pragma unroll
            for (int ol = 0; ol < 2; ol++) {
                int o = o2 * 2 + ol;
                float4 w4r = *(const float4*)(wr + (size_t)(ki * 32 + o) * 4096 + wbase);
                float4 w4i = *(const float4*)(wi + (size_t)(ki * 32 + o) * 4096 + wbase);
                float wrv[4] = {w4r.x, w4r.y, w4r.z, w4r.w};
                float wiv[4] = {w4i.x, w4i.y, w4i.z, w4i.w};
                #pragma unroll
                for (int q = 0; q < 4; q++) {
                    Fr[ol][q] += xr[q] * wrv[q] - xi[q] * wiv[q];
                    Fi[ol][q] += xr[q] * wiv[q] + xi[q] * wrv[q];
                }
            }
        }
        #pragma unroll
        for (int ol = 0; ol < 2; ol++) {
            int o = o2 * 2 + ol;
            #pragma unroll
            for (int q = 0; q < 4; q++) {
                int kz = kzg * 4 + q;
                sA[b * 528 + kz * 33 + o] = make_float2(Fr[ol][q], Fi[ol][q]);
            }
        }
    }
    __syncthreads();
    // phase 3: G[b][kz][co] = sum_o conj(tw[co,o]) * F[b][kz][o]  (tile 8co x 1kz)
    {
        int kz = threadIdx.x & 15, co8 = (threadIdx.x >> 4) & 3, b = threadIdx.x >> 6;
        float gr[8], gi[8];
        #pragma unroll
        for (int j = 0; j < 8; j++) { gr[j] = gi[j] = 0.f; }
        #pragma unroll 4
        for (int o = 0; o < 32; o++) {
            float2 f = sA[b * 528 + kz * 33 + o];
            #pragma unroll
            for (int k = 0; k < 4; k++) {
                float4 tp = twv[o * 16 + co8 * 4 + k];
                gr[2 * k]     += f.x * tp.x + f.y * tp.y;
                gi[2 * k]     += f.y * tp.x - f.x * tp.y;
                gr[2 * k + 1] += f.x * tp.z + f.y * tp.w;
                gi[2 * k + 1] += f.y * tp.z - f.x * tp.w;
            }
        }
        float2* dp = G + (((size_t)(b * 16 + xx) * 16 + ky) * 16 + kz) * 32 + co8 * 8;
        ((float4*)dp)[0] = make_float4(gr[0], gi[0], gr[1], gi[1]);
        ((float4*)dp)[1] = make_float4(gr[2], gi[2], gr[3], gi[3]);
        ((float4*)dp)[2] = make_float4(gr[4], gi[4], gr[5], gi[5]);
        ((float4*)dp)[3] = make_float4(gr[6], gi[6], gr[7], gi[7]);
    }
}

// ---------------- K4: fused z-IDFT + y-IDFT + Re + scale + zero-fill -------
// grid 2048 = (b4, x64, zc8); block 256. x>=16 -> pure zero-fill.
__global__ __launch_bounds__(256) void k_idft_zy(const float2* __restrict__ G,
                                                 float* __restrict__ out) {
    int bid = blockIdx.x;
    int zc = bid & 7, xx = (bid >> 3) & 63, b = bid >> 9;
    float* dstb = out + (size_t)(b * 64 + xx) * 131072;   // [y][z][co]
    if (xx >= 16) {
        float4* d4 = (float4*)dstb;
        for (int t = threadIdx.x; t < 4096; t += 256) {
            int y = t >> 6, r = t & 63;
            d4[(size_t)y * 512 + zc * 64 + r] = make_float4(0.f, 0.f, 0.f, 0.f);
        }
        return;
    }
    __shared__ float2 sH[128 * 34];  // row R=ky*8+dz, stride 34, [co]  ~34KB
    __shared__ float2 twy[1024];     // [ky][y] 8KB
    __shared__ float2 twz[8 * 17];   // [dz][kz] padded
    const float cp = 2.0f * PI_F / 64.0f;
    for (int t = threadIdx.x; t < 1024; t += 256) {
        int ky = t >> 6, y = t & 63;
        float s, c; sincosf(cp * (float)((ky * y) & 63), &s, &c);
        twy[t] = make_float2(c, s);
    }
    if (threadIdx.x < 128) {
        int dz = threadIdx.x >> 4, kz = threadIdx.x & 15;
        int z = zc * 8 + dz;
        float s, c; sincosf(cp * (float)((kz * z) & 63), &s, &c);
        twz[dz * 17 + kz] = make_float2(c, s);
    }
    __syncthreads();
    // phase Z: H[ky][dz][co] = sum_kz twz[dz,kz] * G[ky][kz][co]
    {
        int coh = threadIdx.x & 1, dz = (threadIdx.x >> 1) & 7, ky = threadIdx.x >> 4;
        const float2* Gb = G + ((size_t)(b * 16 + xx) * 16 + ky) * 512 + coh * 16;
        float Hr[16], Hi[16];
        #pragma unroll
        for (int j = 0; j < 16; j++) { Hr[j] = Hi[j] = 0.f; }
        #pragma unroll 2
        for (int kz = 0; kz < 16; kz++) {
            float2 tz = twz[dz * 17 + kz];
            #pragma unroll
            for (int k = 0; k < 8; k++) {
                float4 g = *(const float4*)(Gb + kz * 32 + k * 2);
                Hr[2 * k]     += g.x * tz.x - g.y * tz.y;
                Hi[2 * k]     += g.x * tz.y + g.y * tz.x;
                Hr[2 * k + 1] += g.z * tz.x - g.w * tz.y;
                Hi[2 * k + 1] += g.z * tz.y + g.w * tz.x;
            }
        }
        float2* hp = sH + (ky * 8 + dz) * 34 + coh * 16;
        #pragma unroll
        for (int k = 0; k < 8; k++)
            *(float4*)(hp + k * 2) = make_float4(Hr[2 * k], Hi[2 * k], Hr[2 * k + 1], Hi[2 * k + 1]);
    }
    __syncthreads();
    // phase Y: out[y][dz][co] = Re sum_ky twy[y,ky] * H[ky][dz][co]
    {
        int cog = threadIdx.x & 3, dz = (threadIdx.x >> 2) & 7, yg = threadIdx.x >> 5;
        float acc[8][8];
        #pragma unroll
        for (int yl = 0; yl < 8; yl++)
            #pragma unroll
            for (int cl = 0; cl < 8; cl++) acc[yl][cl] = 0.f;
        const float4* twy4 = (const float4*)twy;
        const float4* sH4 = (const float4*)sH;
        for (int ky = 0; ky < 16; ky++) {
            float4 t0 = twy4[ky * 32 + yg * 4 + 0];
            float4 t1 = twy4[ky * 32 + yg * 4 + 1];
            float4 t2 = twy4[ky * 32 + yg * 4 + 2];
            float4 t3 = twy4[ky * 32 + yg * 4 + 3];
            float4 h0 = sH4[(ky * 8 + dz) * 17 + cog * 4 + 0];
            float4 h1 = sH4[(ky * 8 + dz) * 17 + cog * 4 + 1];
            float4 h2 = sH4[(ky * 8 + dz) * 17 + cog * 4 + 2];
            float4 h3 = sH4[(ky * 8 + dz) * 17 + cog * 4 + 3];
            float tc[8] = {t0.x, t0.z, t1.x, t1.z, t2.x, t2.z, t3.x, t3.z};
            float ts[8] = {t0.y, t0.w, t1.y, t1.w, t2.y, t2.w, t3.y, t3.w};
            float hr[8] = {h0.x, h0.z, h1.x, h1.z, h2.x, h2.z, h3.x, h3.z};
            float hi[8] = {h0.y, h0.w, h1.y, h1.w, h2.y, h2.w, h3.y, h3.w};
            #pragma unroll
            for (int yl = 0; yl < 8; yl++)
                #pragma unroll
                for (int cl = 0; cl < 8; cl++)
                    acc[yl][cl] += tc[yl] * hr[cl] - ts[yl] * hi[cl];
        }
        const float sc = 1.0f / 131072.0f;
        #pragma unroll
        for (int yl = 0; yl < 8; yl++) {
            int y = yg * 8 + yl;
            float4* d4 = (float4*)(dstb + ((size_t)y * 64 + zc * 8 + dz) * 32 + cog * 8);
            d4[0] = make_float4(acc[yl][0] * sc, acc[yl][1] * sc, acc[yl][2] * sc, acc[yl][3] * sc);
            d4[1] = make_float4(acc[yl][4] * sc, acc[yl][5] * sc, acc[yl][6] * sc, acc[yl][7] * sc);
        }
    }
}

extern "C" void kernel_launch(void* const* d_in, const int* in_sizes, int n_in,
                              void* d_out, int out_size, void* d_ws, size_t ws_size,
                              hipStream_t stream) {
    const float* x  = (const float*)d_in[0];
    const float* wr = (const float*)d_in[1];
    const float* wi = (const float*)d_in[2];
    float* out = (float*)d_out;
    char*  ws  = (char*)d_ws;
    // T1: 2,097,152 f2 (16.8 MB); XH: 524,288 f2 (4.2 MB); G: 524,288 f2 (4.2 MB)
    float2* T1 = (float2*)ws;
    float2* XH = (float2*)(ws + (size_t)16777216);
    float2* Gb = (float2*)(ws + (size_t)16777216 + 4194304);

    k_dft_z  <<<1024, 256, 0, stream>>>(x, T1);
    k_dft_y  <<< 512, 256, 0, stream>>>(T1, XH);
    k_mid    <<< 256, 256, 0, stream>>>(XH, wr, wi, Gb);
    k_idft_zy<<<2048, 256, 0, stream>>>(Gb, out);
}